// Round 16
// baseline (4615.243 us; speedup 1.0000x reference)
//
#include <hip/hip_runtime.h>

// ---------------------------------------------------------------------------
// StackedBidirectionalLstm  (B=32, T=512, IN=512, H=512, LAYERS=2, bidir, highway)
//
// Round 16 = round 15's full-K structure with the poll/deposit machinery
// rebuilt exec-mask-proof:
//   - poll loads ALL 4 slots unconditionally each iteration (named v0..v3,
//     no loop-carried asm outputs, no divergent asm) — monotone publication
//     makes the exit iteration's loads fresh for every lane
//   - deposit all chunks uniformly (own member included); own-LDS
//     short-circuit deleted (hl filled by deposits only)
// Structure: 64 WGs x 256 thr = 8 groups (dir x batch-quarter) x 8 members;
// member owns 64 hidden; 4 waves/WG, wave = 16 cols x K=512, wf[5][16] =
// 320 VGPR register-resident; acc IS final ps (no reduction); ONE barrier.
// Exchange: {4 bf16 | 0 | enc} 16B chunks sc0 sc1; S = layer*512+s.
//
//   ws layout (bytes), total 212,074,496 (proven size):
//     px   @ 0          201,326,592  ([2][512*32][3072] bf16, t-major)
//     whp  @ 201326592   10,485,760  (packed Wh fragments)
//     hxc  @ 211812352      262,144  ([2 buf][8 grp][1024 chunks] x 16B)
//   d_out scratch: phase A xbf/wxt0/wxt1, phase B a1bf (as previous rounds).
// ---------------------------------------------------------------------------

typedef float f32x4 __attribute__((ext_vector_type(4)));
typedef __bf16 bf16x8 __attribute__((ext_vector_type(8)));
typedef unsigned short us8 __attribute__((ext_vector_type(8)));
typedef unsigned short us4 __attribute__((ext_vector_type(4)));
typedef unsigned int u32x4 __attribute__((ext_vector_type(4)));

__device__ __forceinline__ unsigned short f2bf(float f) {
  unsigned int u = __float_as_uint(f);
  u += 0x7FFFu + ((u >> 16) & 1u);            // round-to-nearest-even
  return (unsigned short)(u >> 16);
}
__device__ __forceinline__ float bf2f(unsigned int h) {
  return __uint_as_float(h << 16);
}
__device__ __forceinline__ float sigf(float x) { return 1.0f / (1.0f + __expf(-x)); }
__device__ __forceinline__ float tanh_(float x) { return 2.0f / (1.0f + __expf(-2.0f * x)) - 1.0f; }

#define MFMA(a, b, c) __builtin_amdgcn_mfma_f32_16x16x32_bf16((a), (b), (c), 0, 0, 0)
#define GLOAD_LDS(gp, lp)                                                           \
  __builtin_amdgcn_global_load_lds(                                                 \
      (const __attribute__((address_space(1))) void*)(gp),                          \
      (__attribute__((address_space(3))) void*)(lp), 16, 0, 0)

// Coherent (MALL) 16B chunk load; no waitcnt inside.
__device__ __forceinline__ void chunk1_ld(const char* p, u32x4& v) {
  asm volatile("global_load_dwordx4 %0, %1, off sc0 sc1"
               : "=&v"(v) : "v"(p) : "memory");
}
// Fire-and-forget coherent 16B publish.
__device__ __forceinline__ void pub16(char* p, u32x4 v) {
  asm volatile("global_store_dwordx4 %0, %1, off sc0 sc1" :: "v"(p), "v"(v) : "memory");
}

// --------------------------- prep kernels ----------------------------------

__global__ void k_convert_x(const float* __restrict__ x, unsigned short* __restrict__ xb, int n4) {
  int i = blockIdx.x * blockDim.x + threadIdx.x;
  if (i < n4) {
    float4 v = ((const float4*)x)[i];
    us4 o;
    o[0] = f2bf(v.x); o[1] = f2bf(v.y); o[2] = f2bf(v.z); o[3] = f2bf(v.w);
    ((us4*)xb)[i] = o;
  }
}

// Tiled transpose: WxT[n][k] = bf16(Wx[k][n]); z = layer*2+dir
__global__ __launch_bounds__(256) void k_pack_wxT(
    const float* __restrict__ W0, const float* __restrict__ W1,
    const float* __restrict__ W2, const float* __restrict__ W3,
    unsigned short* __restrict__ o01, unsigned short* __restrict__ o23) {
  int y = blockIdx.z;
  int K = (y >> 1) ? 1024 : 512;
  int kb = blockIdx.y * 32;
  if (kb >= K) return;
  const float* W = (y == 0) ? W0 : (y == 1) ? W1 : (y == 2) ? W2 : W3;
  unsigned short* o = (y >> 1) ? (o23 + (size_t)(y & 1) * 3072 * 1024)
                               : (o01 + (size_t)(y & 1) * 3072 * 512);
  __shared__ float tile[32][33];
  int nb = blockIdx.x * 32;
  int tx = threadIdx.x & 31, ty = threadIdx.x >> 5;   // ty 0..7
#pragma unroll
  for (int r = 0; r < 4; ++r)
    tile[ty + r * 8][tx] = W[(size_t)(kb + ty + r * 8) * 3072 + nb + tx];
  __syncthreads();
#pragma unroll
  for (int r = 0; r < 4; ++r)
    o[(size_t)(nb + ty + r * 8) * K + kb + tx] = f2bf(tile[tx][ty + r * 8]);
}

// Pack Wh (512x2560 f32) into MFMA B-fragments:
// out[(((g*32+ns)*16+ks)*64+lane)*8+e] = Wh[ks*32+(lane>>4)*8+e][g*512+ns*16+(lane&15)]
__global__ void k_pack_whp(const float* __restrict__ W0, const float* __restrict__ W1,
                           const float* __restrict__ W2, const float* __restrict__ W3,
                           unsigned short* __restrict__ out) {
  int y = blockIdx.y;
  const float* W = (y == 0) ? W0 : (y == 1) ? W1 : (y == 2) ? W2 : W3;
  unsigned short* o = out + (size_t)y * 1310720;
  int v = blockIdx.x * 256 + threadIdx.x;   // < 163840
  int lane = v & 63, ks = (v >> 6) & 15, ns = (v >> 10) & 31, g = v >> 15;
  int col = g * 512 + ns * 16 + (lane & 15);
  int kb = ks * 32 + ((lane >> 4) << 3);
  us8 vec;
#pragma unroll
  for (int e = 0; e < 8; ++e) vec[e] = f2bf(W[(size_t)(kb + e) * 2560 + col]);
  *(us8*)&o[(size_t)v * 8] = vec;
}

// --------------------------- bf16 GEMM -------------------------------------
// px[rr][col] with rr = t*32+b (t-major), from A[16384][K] @ Bt[3072][K]^T.
__global__ __launch_bounds__(256) void k_gemm(const unsigned short* __restrict__ A,
                                              const unsigned short* __restrict__ BtBase,
                                              unsigned short* __restrict__ CBase, int K) {
  __shared__ __align__(128) unsigned short As[128 * 32];
  __shared__ __align__(128) unsigned short Bs[128 * 32];
  const unsigned short* Bt = BtBase + (size_t)blockIdx.z * 3072 * K;
  unsigned short* C = CBase + (size_t)blockIdx.z * 16384 * 3072;
  int tid = threadIdx.x;
  int w = tid >> 6, l = tid & 63;
  int m0 = blockIdx.x * 128, n0 = blockIdx.y * 128;
  int wr = (w >> 1) * 64, wc = (w & 1) * 64;
  f32x4 acc[4][4];
#pragma unroll
  for (int i = 0; i < 4; ++i)
#pragma unroll
    for (int j = 0; j < 4; ++j) acc[i][j] = (f32x4){0.f, 0.f, 0.f, 0.f};

  for (int k0 = 0; k0 < K; k0 += 32) {
    __syncthreads();
#pragma unroll
    for (int half = 0; half < 2; ++half) {
      int r = w * 32 + half * 16 + (l >> 2);     // row within tile
      int gq = (l & 3) ^ (r & 3);                // swizzled source quarter
      GLOAD_LDS(A + (size_t)(m0 + r) * K + k0 + gq * 8, &As[(w * 32 + half * 16) * 32]);
      GLOAD_LDS(Bt + (size_t)(n0 + r) * K + k0 + gq * 8, &Bs[(w * 32 + half * 16) * 32]);
    }
    __syncthreads();
    bf16x8 af[4], bfr[4];
#pragma unroll
    for (int mi = 0; mi < 4; ++mi) {
      int r = wr + mi * 16 + (l & 15);
      int q = (l >> 4) ^ (r & 3);
      af[mi] = __builtin_bit_cast(bf16x8, *(const us8*)&As[r * 32 + q * 8]);
    }
#pragma unroll
    for (int ni = 0; ni < 4; ++ni) {
      int r = wc + ni * 16 + (l & 15);
      int q = (l >> 4) ^ (r & 3);
      bfr[ni] = __builtin_bit_cast(bf16x8, *(const us8*)&Bs[r * 32 + q * 8]);
    }
#pragma unroll
    for (int mi = 0; mi < 4; ++mi)
#pragma unroll
      for (int ni = 0; ni < 4; ++ni) acc[mi][ni] = MFMA(af[mi], bfr[ni], acc[mi][ni]);
  }
#pragma unroll
  for (int mi = 0; mi < 4; ++mi)
#pragma unroll
    for (int ni = 0; ni < 4; ++ni)
#pragma unroll
      for (int r4 = 0; r4 < 4; ++r4) {
        int row = m0 + wr + mi * 16 + (l >> 4) * 4 + r4;    // b*512 + t
        int rr = ((row & 511) << 5) + (row >> 9);           // t*32 + b
        int col = n0 + wc + ni * 16 + (l & 15);
        C[(size_t)rr * 3072 + col] = f2bf(acc[mi][ni][r4]);
      }
}

// --------------------------- persistent LSTM layer -------------------------
// 64 WGs x 256 threads = 8 groups (dir d, batch-quarter q) x 8 members.
// Member m owns hidden m*64..m*64+63. 4 waves: wave wv = 16-col block,
// full K=512 -> wf[5][16] = 320 VGPR. acc = final ps (no reduction).
// Exchange: 1024 chunks/group {4 bf16|0|enc}; 4 slots/thread, polled
// unconditionally (no divergent asm); deposit all; ONE barrier/step.
__global__ __launch_bounds__(256, 1) void k_persist(
    const unsigned short* __restrict__ px,    // [2][512*32][3072] bf16 t-major
    const unsigned short* __restrict__ wp,    // this layer's packed Wh (2 dirs)
    const float* __restrict__ bias_f, const float* __restrict__ bias_b,
    char* __restrict__ hxc,                   // [2 buf][8 grp][1024 chunks]x16B
    unsigned short* __restrict__ ybf,         // layer0: a1bf, else null
    float* __restrict__ yf,                   // layer1: d_out, else null
    float* __restrict__ finals,               // d_out + 16777216
    int layer) {
  __shared__ unsigned short hl[2][8 * 520];   // 16.25 KiB parity h images
  int wg = blockIdx.x;
  int grp = wg >> 3, m = wg & 7;
  int d = grp & 1, q = grp >> 1;
  int tid = threadIdx.x;
  int wv = tid >> 6, l = tid & 63;
  int ns = m * 4 + wv;                        // 16-col slice id (0..31)
  const unsigned short* wpd = wp + (size_t)d * 1310720;
  const unsigned short* pxd = px + (size_t)d * 16384 * 3072;
  const float* bias = d ? bias_b : bias_f;
  char* hxg = hxc + (size_t)grp * 16384;      // + buf*131072

  // ---- Wh fragments register-resident: wf[gate][kf], FULL K=512 ----
  bf16x8 wf[5][16];
#pragma unroll
  for (int g5 = 0; g5 < 5; ++g5)
#pragma unroll
    for (int kf = 0; kf < 16; ++kf)
      wf[g5][kf] = __builtin_bit_cast(
          bf16x8, *(const us8*)&wpd[(size_t)((g5 * 32 + ns) * 16 + kf) * 512 + l * 8]);

  // ---- epilogue mapping: 2 outputs/lane via dup-row property ----
  int hsel = l >> 4;                          // 0..3
  int r0 = (hsel == 0) ? 0 : (hsel == 1) ? 4 : (hsel == 2) ? 2 : 6;
  int r1 = r0 + 1;
  bool hi2 = (hsel & 2) != 0;                 // acc elems 2,3 vs 0,1
  int j = l & 15, jg = m * 64 + wv * 16 + j;  // hidden index (0..511)
  int b0 = q * 8 + r0, b1 = q * 8 + r1;
  float bv[5];
#pragma unroll
  for (int g5 = 0; g5 < 5; ++g5) bv[g5] = bias[(g5 << 9) + jg];

  float c0 = 0.f, c1 = 0.f;
  unsigned int xC0[6], xN0[6], xC1[6], xN1[6];
  {
    int t0 = d ? 511 : 0;
    const unsigned short* p0 = pxd + ((size_t)((t0 << 5) + b0)) * 3072 + jg;
    const unsigned short* p1 = pxd + ((size_t)((t0 << 5) + b1)) * 3072 + jg;
#pragma unroll
    for (int q6 = 0; q6 < 6; ++q6) { xN0[q6] = p0[q6 << 9]; xN1[q6] = p1[q6 << 9]; }
  }

  // ---- poll slots: chunks cs = tid + 256k; deposit offsets ----
  int cs0 = tid, cs1 = tid + 256, cs2 = tid + 512, cs3 = tid + 768;
  int dep0 = ((cs0 >> 4) & 7) * 520 + (cs0 >> 7) * 64 + (cs0 & 15) * 4;
  int dep1 = ((cs1 >> 4) & 7) * 520 + (cs1 >> 7) * 64 + (cs1 & 15) * 4;
  int dep2 = ((cs2 >> 4) & 7) * 520 + (cs2 >> 7) * 64 + (cs2 & 15) * 4;
  int dep3 = ((cs3 >> 4) & 7) * 520 + (cs3 >> 7) * 64 + (cs3 & 15) * 4;

  // ---- publish mapping: lanes 0..31 -> chunk (row pr, quad pcq) ----
  int pr = l >> 2, pcq = l & 3;               // valid for l < 32
  int pbaseL = ((pr & 2) ? 32 : 0) + ((pr & 4) ? 16 : 0);
  bool prOdd = (pr & 1) != 0;

  // ---- A-fragment LDS base: row (l&7 clamp), k-sub (l>>4)*8 ----
  int abase = (l & 7) * 520 + ((l >> 4) << 3);

  int Sbase = layer * 512;

  for (int s = 0; s < 512; ++s) {
    int t = d ? (511 - s) : s;
    int par = s & 1;

    // ---- uniform poll + deposit (skip s=0: h0 == 0) ----
    if (s > 0) {
      const char* cb = hxg + (size_t)par * 131072;
      unsigned S = (unsigned)(Sbase + s);
      unsigned enc = S | ((~S & 0xFFFF) << 16);
      u32x4 v0, v1, v2, v3;
      long guard = 0;
      bool first = true, ok;
      do {
        if (!first) __builtin_amdgcn_s_sleep(1);
        first = false;
        chunk1_ld(cb + (size_t)cs0 * 16, v0);
        chunk1_ld(cb + (size_t)cs1 * 16, v1);
        chunk1_ld(cb + (size_t)cs2 * 16, v2);
        chunk1_ld(cb + (size_t)cs3 * 16, v3);
        asm volatile("s_waitcnt vmcnt(0)" ::: "memory");
        __builtin_amdgcn_sched_barrier(0);
        bool mine = (v0[3] == enc) && (v1[3] == enc) &&
                    (v2[3] == enc) && (v3[3] == enc);
        ok = (__all((int)mine) != 0);
      } while (!ok && ++guard < 300000L);
      {
        unsigned int* pw = (unsigned int*)&hl[par][dep0];
        pw[0] = v0[0]; pw[1] = v0[1];
      }
      {
        unsigned int* pw = (unsigned int*)&hl[par][dep1];
        pw[0] = v1[0]; pw[1] = v1[1];
      }
      {
        unsigned int* pw = (unsigned int*)&hl[par][dep2];
        pw[0] = v2[0]; pw[1] = v2[1];
      }
      {
        unsigned int* pw = (unsigned int*)&hl[par][dep3];
        pw[0] = v3[0]; pw[1] = v3[1];
      }
    }

    // ---- px: promote prefetch, issue next (compiler-managed waits) ----
#pragma unroll
    for (int i = 0; i < 6; ++i) { xC0[i] = xN0[i]; xC1[i] = xN1[i]; }
    if (s < 511) {
      int tn = d ? (511 - (s + 1)) : (s + 1);
      const unsigned short* p0 = pxd + ((size_t)((tn << 5) + b0)) * 3072 + jg;
      const unsigned short* p1 = pxd + ((size_t)((tn << 5) + b1)) * 3072 + jg;
#pragma unroll
      for (int q6 = 0; q6 < 6; ++q6) { xN0[q6] = p0[q6 << 9]; xN1[q6] = p1[q6 << 9]; }
    }

    __syncthreads();                          // THE barrier: hl[par] complete

    // ---- MFMA: M=8(pad16) x N=80 x K=512, acc = final ps ----
    f32x4 acc[5];
#pragma unroll
    for (int g5 = 0; g5 < 5; ++g5) acc[g5] = (f32x4){0.f, 0.f, 0.f, 0.f};
    if (s > 0) {
#pragma unroll
      for (int kf = 0; kf < 16; ++kf) {
        bf16x8 av = __builtin_bit_cast(bf16x8, *(const us8*)&hl[par][abase + kf * 32]);
#pragma unroll
        for (int g5 = 0; g5 < 5; ++g5) acc[g5] = MFMA(av, wf[g5][kf], acc[g5]);
      }
    }

    // ---- epilogue: 2 outputs/lane, no reduction ----
    float ps0[5], ps1[5];
#pragma unroll
    for (int g5 = 0; g5 < 5; ++g5) {
      ps0[g5] = (hi2 ? acc[g5][2] : acc[g5][0]) + bv[g5];
      ps1[g5] = (hi2 ? acc[g5][3] : acc[g5][1]) + bv[g5];
    }
    float ht0, ht1, cn0, cn1;
    {
      float x0 = bf2f(xC0[0]), x1 = bf2f(xC0[1]), x2 = bf2f(xC0[2]);
      float x3 = bf2f(xC0[3]), x4 = bf2f(xC0[4]), x5 = bf2f(xC0[5]);
      float iG = sigf(x0 + ps0[0]);
      float fG = sigf(x1 + ps0[1]);
      float gG = tanh_(x2 + ps0[2]);
      float oG = sigf(x3 + ps0[3]);
      cn0 = iG * gG + fG * c0;
      c0 = cn0;
      ht0 = oG * tanh_(cn0);
      float rG = sigf(x4 + ps0[4]);
      ht0 = rG * ht0 + (1.f - rG) * x5;
    }
    {
      float x0 = bf2f(xC1[0]), x1 = bf2f(xC1[1]), x2 = bf2f(xC1[2]);
      float x3 = bf2f(xC1[3]), x4 = bf2f(xC1[4]), x5 = bf2f(xC1[5]);
      float iG = sigf(x0 + ps1[0]);
      float fG = sigf(x1 + ps1[1]);
      float gG = tanh_(x2 + ps1[2]);
      float oG = sigf(x3 + ps1[3]);
      cn1 = iG * gG + fG * c1;
      c1 = cn1;
      ht1 = oG * tanh_(cn1);
      float rG = sigf(x4 + ps1[4]);
      ht1 = rG * ht1 + (1.f - rG) * x5;
    }

    // ---- publish FIRST (all consumers' critical path) ----
    unsigned int h0b = (unsigned int)f2bf(ht0);
    unsigned int h1b = (unsigned int)f2bf(ht1);
    if (s < 511) {
      unsigned int vals[4];
#pragma unroll
      for (int e4 = 0; e4 < 4; ++e4) {
        int srcl = pbaseL + pcq * 4 + e4;
        unsigned int a = __shfl(h0b, srcl);
        unsigned int bq = __shfl(h1b, srcl);
        vals[e4] = prOdd ? bq : a;
      }
      if (l < 32) {
        unsigned S1 = (unsigned)(Sbase + s + 1);
        unsigned enc1 = S1 | ((~S1 & 0xFFFF) << 16);
        char* dst = hxg + (size_t)((s + 1) & 1) * 131072 +
                    (size_t)(((m * 8 + pr) * 16) + wv * 4 + pcq) * 16;
        u32x4 pv = {vals[0] | (vals[1] << 16), vals[2] | (vals[3] << 16), 0u, enc1};
        pub16(dst, pv);
      }
    }

    // ---- y / finals ----
    size_t yo0 = ((size_t)(b0 * 512 + t)) * 1024 + d * 512 + jg;
    size_t yo1 = ((size_t)(b1 * 512 + t)) * 1024 + d * 512 + jg;
    if (ybf) { ybf[yo0] = (unsigned short)h0b; ybf[yo1] = (unsigned short)h1b; }
    else     { yf[yo0] = ht0; yf[yo1] = ht1; }
    if (s == 511) {
      int fo0 = (layer * 32 + b0) * 1024 + d * 512 + jg;
      int fo1 = (layer * 32 + b1) * 1024 + d * 512 + jg;
      finals[fo0] = ht0; finals[65536 + fo0] = cn0;
      finals[fo1] = ht1; finals[65536 + fo1] = cn1;
    }
  }
}

// --------------------------- host ------------------------------------------

extern "C" void kernel_launch(void* const* d_in, const int* in_sizes, int n_in,
                              void* d_out, int out_size, void* d_ws, size_t ws_size,
                              hipStream_t stream) {
  (void)in_sizes; (void)n_in; (void)out_size; (void)ws_size;
  const float* x = (const float*)d_in[0];
  const float* Wx[4] = {(const float*)d_in[1], (const float*)d_in[4],
                        (const float*)d_in[7], (const float*)d_in[10]};
  const float* Wh[4] = {(const float*)d_in[2], (const float*)d_in[5],
                        (const float*)d_in[8], (const float*)d_in[11]};
  const float* bs[4] = {(const float*)d_in[3], (const float*)d_in[6],
                        (const float*)d_in[9], (const float*)d_in[12]};

  // ws: px + packed Wh + chunk exchange (total = 212,074,496 B, proven)
  char* ws = (char*)d_ws;
  unsigned short* px   = (unsigned short*)(ws);
  unsigned short* whp  = (unsigned short*)(ws + 201326592);
  char*           hxc  = (char*)(ws + 211812352);

  // d_out doubles as scratch for transients (all dead before final y writes)
  char* ob = (char*)d_out;
  unsigned short* xbf  = (unsigned short*)(ob);             // 16 MiB, phase A
  unsigned short* wxt0 = (unsigned short*)(ob + 16777216);  // 6 MiB, phase A
  unsigned short* wxt1 = (unsigned short*)(ob + 33554432);  // 12 MiB
  unsigned short* a1bf = (unsigned short*)(ob);             // 32 MiB, phase B
  float* out = (float*)d_out;
  float* finals = out + 16777216;

  k_convert_x<<<8192, 256, 0, stream>>>(x, xbf, 2097152);
  k_pack_wxT<<<dim3(96, 32, 4), 256, 0, stream>>>(Wx[0], Wx[1], Wx[2], Wx[3], wxt0, wxt1);
  k_pack_whp<<<dim3(640, 4), 256, 0, stream>>>(Wh[0], Wh[1], Wh[2], Wh[3], whp);
  hipMemsetAsync(hxc, 0xFF, 262144, stream);   // never decodes as a valid seq

  for (int layer = 0; layer < 2; ++layer) {
    int K = layer ? 1024 : 512;
    const unsigned short* Ag = layer ? a1bf : xbf;
    const unsigned short* wxt = layer ? wxt1 : wxt0;
    k_gemm<<<dim3(128, 24, 2), 256, 0, stream>>>(Ag, wxt, px, K);
    k_persist<<<64, 256, 0, stream>>>(
        px, whp + (size_t)layer * 2621440, bs[layer * 2], bs[layer * 2 + 1],
        hxc, layer ? nullptr : a1bf, layer ? out : nullptr, finals, layer);
  }
}

// Round 17
// 2642.365 us; speedup vs baseline: 1.7466x; 1.7466x over previous
//
#include <hip/hip_runtime.h>

// ---------------------------------------------------------------------------
// StackedBidirectionalLstm  (B=32, T=512, IN=512, H=512, LAYERS=2, bidir, highway)
//
// Round 17 = round 14 verbatim (best passing: 2637 us). Terminal revert after
// the full-K arc (r15/r16) died on register-allocator caps and phase-
// alternation (r11/r12) regressed. Structure: 128 WGs x 512 thr = 8 groups
// (dir x batch-quarter) x 16 members; MALL chunk exchange {6 bf16 | enc(s)}
// sc0 sc1 poll-on-data, partition-polled 1-2 chunks/thread; own-member
// short-circuit through LDS; px register double-buffer; 2 barriers/step.
// Per-step cost ~2.21 us = MALL publish->discover RTT chain (sync floor).
//
//   ws layout (bytes), total ~202.4 MiB:
//     px   @ 0          201,326,592  ([2][512*32][3072] bf16, t-major)
//     whp  @ 201326592   10,485,760  (packed Wh fragments)
//     hxc  @ 211812352      393,216  ([2 layer][2 buf][8 grp][16 m][8 r][6 c]x16B)
//   d_out scratch: phase A xbf/wxt0/wxt1, phase B a1bf.
// ---------------------------------------------------------------------------

typedef float f32x4 __attribute__((ext_vector_type(4)));
typedef __bf16 bf16x8 __attribute__((ext_vector_type(8)));
typedef unsigned short us8 __attribute__((ext_vector_type(8)));
typedef unsigned short us4 __attribute__((ext_vector_type(4)));
typedef unsigned int u32x4 __attribute__((ext_vector_type(4)));

__device__ __forceinline__ unsigned short f2bf(float f) {
  unsigned int u = __float_as_uint(f);
  u += 0x7FFFu + ((u >> 16) & 1u);            // round-to-nearest-even
  return (unsigned short)(u >> 16);
}
__device__ __forceinline__ float bf2f(unsigned int h) {
  return __uint_as_float(h << 16);
}
__device__ __forceinline__ float sigf(float x) { return 1.0f / (1.0f + __expf(-x)); }
__device__ __forceinline__ float tanh_(float x) { return 2.0f / (1.0f + __expf(-2.0f * x)) - 1.0f; }

#define MFMA(a, b, c) __builtin_amdgcn_mfma_f32_16x16x32_bf16((a), (b), (c), 0, 0, 0)
#define GLOAD_LDS(gp, lp)                                                           \
  __builtin_amdgcn_global_load_lds(                                                 \
      (const __attribute__((address_space(1))) void*)(gp),                          \
      (__attribute__((address_space(3))) void*)(lp), 16, 0, 0)

// Coherent (MALL) 16B chunk load; no waitcnt inside.
__device__ __forceinline__ void chunk1_ld(const char* p, u32x4& v) {
  asm volatile("global_load_dwordx4 %0, %1, off sc0 sc1"
               : "=&v"(v) : "v"(p) : "memory");
}
// Fire-and-forget coherent 16B publish.
__device__ __forceinline__ void pub16(char* p, u32x4 v) {
  asm volatile("global_store_dwordx4 %0, %1, off sc0 sc1" :: "v"(p), "v"(v) : "memory");
}

// --------------------------- prep kernels ----------------------------------

__global__ void k_convert_x(const float* __restrict__ x, unsigned short* __restrict__ xb, int n4) {
  int i = blockIdx.x * blockDim.x + threadIdx.x;
  if (i < n4) {
    float4 v = ((const float4*)x)[i];
    us4 o;
    o[0] = f2bf(v.x); o[1] = f2bf(v.y); o[2] = f2bf(v.z); o[3] = f2bf(v.w);
    ((us4*)xb)[i] = o;
  }
}

// Tiled transpose: WxT[n][k] = bf16(Wx[k][n]); z = layer*2+dir
__global__ __launch_bounds__(256) void k_pack_wxT(
    const float* __restrict__ W0, const float* __restrict__ W1,
    const float* __restrict__ W2, const float* __restrict__ W3,
    unsigned short* __restrict__ o01, unsigned short* __restrict__ o23) {
  int y = blockIdx.z;
  int K = (y >> 1) ? 1024 : 512;
  int kb = blockIdx.y * 32;
  if (kb >= K) return;
  const float* W = (y == 0) ? W0 : (y == 1) ? W1 : (y == 2) ? W2 : W3;
  unsigned short* o = (y >> 1) ? (o23 + (size_t)(y & 1) * 3072 * 1024)
                               : (o01 + (size_t)(y & 1) * 3072 * 512);
  __shared__ float tile[32][33];
  int nb = blockIdx.x * 32;
  int tx = threadIdx.x & 31, ty = threadIdx.x >> 5;   // ty 0..7
#pragma unroll
  for (int r = 0; r < 4; ++r)
    tile[ty + r * 8][tx] = W[(size_t)(kb + ty + r * 8) * 3072 + nb + tx];
  __syncthreads();
#pragma unroll
  for (int r = 0; r < 4; ++r)
    o[(size_t)(nb + ty + r * 8) * K + kb + tx] = f2bf(tile[tx][ty + r * 8]);
}

// Pack Wh (512x2560 f32) into MFMA B-fragments:
// out[(((g*32+ns)*16+ks)*64+lane)*8+e] = Wh[ks*32+(lane>>4)*8+e][g*512+ns*16+(lane&15)]
__global__ void k_pack_whp(const float* __restrict__ W0, const float* __restrict__ W1,
                           const float* __restrict__ W2, const float* __restrict__ W3,
                           unsigned short* __restrict__ out) {
  int y = blockIdx.y;
  const float* W = (y == 0) ? W0 : (y == 1) ? W1 : (y == 2) ? W2 : W3;
  unsigned short* o = out + (size_t)y * 1310720;
  int v = blockIdx.x * 256 + threadIdx.x;   // < 163840
  int lane = v & 63, ks = (v >> 6) & 15, ns = (v >> 10) & 31, g = v >> 15;
  int col = g * 512 + ns * 16 + (lane & 15);
  int kb = ks * 32 + ((lane >> 4) << 3);
  us8 vec;
#pragma unroll
  for (int e = 0; e < 8; ++e) vec[e] = f2bf(W[(size_t)(kb + e) * 2560 + col]);
  *(us8*)&o[(size_t)v * 8] = vec;
}

// --------------------------- bf16 GEMM -------------------------------------
// px[rr][col] with rr = t*32+b (t-major), from A[16384][K] @ Bt[3072][K]^T.
__global__ __launch_bounds__(256) void k_gemm(const unsigned short* __restrict__ A,
                                              const unsigned short* __restrict__ BtBase,
                                              unsigned short* __restrict__ CBase, int K) {
  __shared__ __align__(128) unsigned short As[128 * 32];
  __shared__ __align__(128) unsigned short Bs[128 * 32];
  const unsigned short* Bt = BtBase + (size_t)blockIdx.z * 3072 * K;
  unsigned short* C = CBase + (size_t)blockIdx.z * 16384 * 3072;
  int tid = threadIdx.x;
  int w = tid >> 6, l = tid & 63;
  int m0 = blockIdx.x * 128, n0 = blockIdx.y * 128;
  int wr = (w >> 1) * 64, wc = (w & 1) * 64;
  f32x4 acc[4][4];
#pragma unroll
  for (int i = 0; i < 4; ++i)
#pragma unroll
    for (int j = 0; j < 4; ++j) acc[i][j] = (f32x4){0.f, 0.f, 0.f, 0.f};

  for (int k0 = 0; k0 < K; k0 += 32) {
    __syncthreads();
#pragma unroll
    for (int half = 0; half < 2; ++half) {
      int r = w * 32 + half * 16 + (l >> 2);     // row within tile
      int gq = (l & 3) ^ (r & 3);                // swizzled source quarter
      GLOAD_LDS(A + (size_t)(m0 + r) * K + k0 + gq * 8, &As[(w * 32 + half * 16) * 32]);
      GLOAD_LDS(Bt + (size_t)(n0 + r) * K + k0 + gq * 8, &Bs[(w * 32 + half * 16) * 32]);
    }
    __syncthreads();
    bf16x8 af[4], bfr[4];
#pragma unroll
    for (int mi = 0; mi < 4; ++mi) {
      int r = wr + mi * 16 + (l & 15);
      int q = (l >> 4) ^ (r & 3);
      af[mi] = __builtin_bit_cast(bf16x8, *(const us8*)&As[r * 32 + q * 8]);
    }
#pragma unroll
    for (int ni = 0; ni < 4; ++ni) {
      int r = wc + ni * 16 + (l & 15);
      int q = (l >> 4) ^ (r & 3);
      bfr[ni] = __builtin_bit_cast(bf16x8, *(const us8*)&Bs[r * 32 + q * 8]);
    }
#pragma unroll
    for (int mi = 0; mi < 4; ++mi)
#pragma unroll
      for (int ni = 0; ni < 4; ++ni) acc[mi][ni] = MFMA(af[mi], bfr[ni], acc[mi][ni]);
  }
#pragma unroll
  for (int mi = 0; mi < 4; ++mi)
#pragma unroll
    for (int ni = 0; ni < 4; ++ni)
#pragma unroll
      for (int r4 = 0; r4 < 4; ++r4) {
        int row = m0 + wr + mi * 16 + (l >> 4) * 4 + r4;    // b*512 + t
        int rr = ((row & 511) << 5) + (row >> 9);           // t*32 + b
        int col = n0 + wc + ni * 16 + (l & 15);
        C[(size_t)rr * 3072 + col] = f2bf(acc[mi][ni][r4]);
      }
}

// --------------------------- persistent LSTM layer -------------------------
// 128 WGs x 512 threads = 8 groups (dir d, batch-quarter q) x 16 members.
// Member m owns hidden units m*32..m*32+31. 8 waves: kh = w&3 (K quarter),
// nh = w>>2 (hidden half). Exchange: 768 chunks/group {6 bf16 | enc(s)};
// own member's 48 chunks short-circuit through LDS; foreign chunks
// partition-polled 1-2/thread and deposited into hl.
// hl layout: [8 rows][16 membs x 40 elems, row stride 648].
__global__ __launch_bounds__(512, 1) void k_persist(
    const unsigned short* __restrict__ px,    // [2][512*32][3072] bf16 t-major
    const unsigned short* __restrict__ wp,    // this layer's packed Wh (2 dirs)
    const float* __restrict__ bias_f, const float* __restrict__ bias_b,
    char* __restrict__ hxc,                   // [2 layer][2 buf][8 grp][16 m][8 r][6 c]x16B
    unsigned short* __restrict__ ybf,         // layer0: a1bf, else null
    float* __restrict__ yf,                   // layer1: d_out, else null
    float* __restrict__ finals,               // d_out + 16777216
    int layer) {
  __shared__ float part[2][4][8][160];        // 40 KiB, parity-buffered
  __shared__ unsigned short hl[8 * 648];      // 10.125 KiB h image
  int wg = blockIdx.x;
  int grp = wg >> 4, m = wg & 15;
  int d = grp & 1, q = grp >> 1;
  int tid = threadIdx.x;
  int w = tid >> 6, l = tid & 63;
  int kh = w & 3, nh = w >> 2;
  int ns = m * 2 + nh;                        // 16-hidden slice id (0..31)
  const unsigned short* wpd = wp + (size_t)d * 1310720;
  const unsigned short* pxd = px + (size_t)d * 16384 * 3072;
  const float* bias = d ? bias_b : bias_f;
  char* hxg = hxc + (size_t)layer * 196608 + (size_t)grp * 12288;

  // ---- Wh fragments: wf[gate][kk], this wave's K-quarter ----
  bf16x8 wf[5][4];
#pragma unroll
  for (int g5 = 0; g5 < 5; ++g5)
#pragma unroll
    for (int kk = 0; kk < 4; ++kk)
      wf[g5][kk] = __builtin_bit_cast(
          bf16x8,
          *(const us8*)&wpd[(size_t)((g5 * 32 + ns) * 16 + (kh * 4 + kk)) * 512 + l * 8]);

  // ---- epilogue constants (threads 0..255 = waves 0..3) ----
  bool epi = tid < 256;
  int r = tid >> 5, j = tid & 31, jg = m * 32 + j, b = q * 8 + r;
  float bv[5];
#pragma unroll
  for (int g5 = 0; g5 < 5; ++g5) bv[g5] = bias[(g5 << 9) + jg];

  float c = 0.f;
  unsigned int xCur[6], xNext[6];             // px register double-buffer
  if (epi) {
    int t0 = d ? 511 : 0;
    const unsigned short* pp = pxd + ((size_t)((t0 << 5) + b)) * 3072 + jg;
#pragma unroll
    for (int q6 = 0; q6 < 6; ++q6) xNext[q6] = pp[q6 << 9];
  }

  // ---- partition-poll assignment: chunks c0 = tid, c1 = 512+tid (tid<256)
  int c0 = tid;
  int c1 = 512 + tid;
  bool has1 = tid < 256;
  int m8r0 = c0 / 6, myc0 = c0 - m8r0 * 6;
  bool own0 = (c0 / 48) == m;                 // own member's chunk
  int off0 = (m8r0 & 7) * 648 + (m8r0 >> 3) * 40 + myc0 * 6;   // elems
  bool is5_0 = (myc0 == 5);
  int m8r1 = c1 / 6, myc1 = c1 - m8r1 * 6;
  bool own1 = (c1 / 48) == m;
  int off1 = (m8r1 & 7) * 648 + (m8r1 >> 3) * 40 + myc1 * 6;
  bool is5_1 = (myc1 == 5);

  int myc = l & 31, pbase = l & 32, prow = 2 * w + (l >> 5);  // publish (waves 0..3)

  for (int s = 0; s < 512; ++s) {
    int t = d ? (511 - s) : s;

    // ---- partition-poll + LDS deposit (foreign chunks only; skip s=0) ----
    if (s > 0) {
      const char* cb = hxg + (size_t)(s & 1) * 98304;
      const char* a0 = cb + (size_t)c0 * 16;
      const char* a1 = cb + (size_t)c1 * 16;
      unsigned enc = (unsigned)(s | ((~s & 0xFFFF) << 16));
      u32x4 v0, v1;
      bool d0 = own0, d1 = !has1 || own1;
      long guard = 0;
      bool first = true, ok;
      do {
        if (!first) __builtin_amdgcn_s_sleep(1);   // throttle retry traffic
        first = false;
        if (!d0) chunk1_ld(a0, v0);
        if (!d1) chunk1_ld(a1, v1);
        asm volatile("s_waitcnt vmcnt(0)" ::: "memory");
        __builtin_amdgcn_sched_barrier(0);
        d0 = d0 || (v0[3] == enc);
        d1 = d1 || (v1[3] == enc);
        ok = (__all((int)(d0 && d1)) != 0);
      } while (!ok && ++guard < 300000L);
      // deposit foreign payloads (dword-aligned LDS writes)
      if (!own0) {
        unsigned int* pw = (unsigned int*)((char*)hl + off0 * 2);
        pw[0] = v0[0];
        if (!is5_0) { pw[1] = v0[1]; pw[2] = v0[2]; }
      }
      if (has1 && !own1) {
        unsigned int* pw1 = (unsigned int*)((char*)hl + off1 * 2);
        pw1[0] = v1[0];
        if (!is5_1) { pw1[1] = v1[1]; pw1[2] = v1[2]; }
      }
    }

    // ---- px: promote prefetch, issue next (compiler-managed waits) ----
    if (epi) {
#pragma unroll
      for (int i = 0; i < 6; ++i) xCur[i] = xNext[i];   // loads are 1 iter old
      if (s < 511) {
        int tn = d ? (511 - (s + 1)) : (s + 1);
        const unsigned short* pp = pxd + ((size_t)((tn << 5) + b)) * 3072 + jg;
#pragma unroll
        for (int q6 = 0; q6 < 6; ++q6) xNext[q6] = pp[q6 << 9];
      }
    }

    __syncthreads();                          // B1: hl image complete

    // ---- MFMA: M=8(pad16) x N=80 x K=128 per wave, A-frags from LDS ----
    f32x4 acc[5];
#pragma unroll
    for (int g5 = 0; g5 < 5; ++g5) acc[g5] = (f32x4){0.f, 0.f, 0.f, 0.f};
    if (s > 0) {
#pragma unroll
      for (int kk = 0; kk < 4; ++kk) {
        bf16x8 av = __builtin_bit_cast(
            bf16x8,
            *(const us8*)&hl[(l & 7) * 648 + (4 * kh + kk) * 40 + ((l >> 4) << 3)]);
#pragma unroll
        for (int g5 = 0; g5 < 5; ++g5) acc[g5] = MFMA(av, wf[g5][kk], acc[g5]);
      }
    }
    if (l < 32) {
#pragma unroll
      for (int g5 = 0; g5 < 5; ++g5)
#pragma unroll
        for (int r4 = 0; r4 < 4; ++r4)
          part[s & 1][kh][(l >> 4) * 4 + r4][nh * 80 + g5 * 16 + (l & 15)] = acc[g5][r4];
    }
    __syncthreads();                          // B2: part ready

    // ---- epilogue + publish (threads 0..255) ----
    if (epi) {
      int cc0 = (j >> 4) * 80 + (j & 15);
      float ps_[5];
#pragma unroll
      for (int g5 = 0; g5 < 5; ++g5) {
        int cc = cc0 + g5 * 16;
        ps_[g5] = part[s & 1][0][r][cc] + part[s & 1][1][r][cc] +
                  part[s & 1][2][r][cc] + part[s & 1][3][r][cc] + bv[g5];
      }
      float x0 = bf2f(xCur[0]), x1 = bf2f(xCur[1]), x2 = bf2f(xCur[2]);
      float x3 = bf2f(xCur[3]), x4 = bf2f(xCur[4]), x5 = bf2f(xCur[5]);
      float iG = sigf(x0 + ps_[0]);
      float fG = sigf(x1 + ps_[1]);
      float gG = tanh_(x2 + ps_[2]);
      float oG = sigf(x3 + ps_[3]);
      float cn = iG * gG + fG * c;
      c = cn;
      float ht = oG * tanh_(cn);
      float rG = sigf(x4 + ps_[4]);
      ht = rG * ht + (1.f - rG) * x5;

      // publish FIRST (foreign members' next-step critical path)
      unsigned short hb16 = f2bf(ht);
      if (s < 511) {
        unsigned int hbits = (unsigned int)hb16;
        unsigned int vv[6];
#pragma unroll
        for (int i = 0; i < 6; ++i)
          vv[i] = __shfl(hbits, (pbase + myc * 6 + i) & 63);
        unsigned int pw0 = vv[0] | (vv[1] << 16);
        unsigned int pw1 = vv[2] | (vv[3] << 16);
        unsigned int pw2 = vv[4] | (vv[5] << 16);
        if (myc == 5) { pw1 = 0; pw2 = 0; }
        if (myc < 6) {
          char* dst = hxg + (size_t)((s + 1) & 1) * 98304 +
                      (size_t)((m * 8 + prow) * 6 + myc) * 16;
          unsigned enc1 = (unsigned)((s + 1) | ((~(s + 1) & 0xFFFF) << 16));
          u32x4 pv = {pw0, pw1, pw2, enc1};
          pub16(dst, pv);
        }
        // own-member short-circuit: next step's hl comes straight from LDS
        hl[r * 648 + m * 40 + j] = hb16;
      }

      size_t yo = ((size_t)(b * 512 + t)) * 1024 + d * 512 + jg;
      if (ybf) ybf[yo] = hb16;
      else     yf[yo] = ht;
      if (s == 511) {
        int fo = (layer * 32 + b) * 1024 + d * 512 + jg;
        finals[fo] = ht;            // final_h
        finals[65536 + fo] = cn;    // final_c
      }
    }
  }
}

// --------------------------- host ------------------------------------------

extern "C" void kernel_launch(void* const* d_in, const int* in_sizes, int n_in,
                              void* d_out, int out_size, void* d_ws, size_t ws_size,
                              hipStream_t stream) {
  (void)in_sizes; (void)n_in; (void)out_size; (void)ws_size;
  const float* x = (const float*)d_in[0];
  const float* Wx[4] = {(const float*)d_in[1], (const float*)d_in[4],
                        (const float*)d_in[7], (const float*)d_in[10]};
  const float* Wh[4] = {(const float*)d_in[2], (const float*)d_in[5],
                        (const float*)d_in[8], (const float*)d_in[11]};
  const float* bs[4] = {(const float*)d_in[3], (const float*)d_in[6],
                        (const float*)d_in[9], (const float*)d_in[12]};

  // ws: px + packed Wh + chunk exchange (~202.4 MiB)
  char* ws = (char*)d_ws;
  unsigned short* px   = (unsigned short*)(ws);
  unsigned short* whp  = (unsigned short*)(ws + 201326592);
  char*           hxc  = (char*)(ws + 211812352);

  // d_out doubles as scratch for transients (all dead before final y writes)
  char* ob = (char*)d_out;
  unsigned short* xbf  = (unsigned short*)(ob);             // 16 MiB, phase A
  unsigned short* wxt0 = (unsigned short*)(ob + 16777216);  // 6 MiB, phase A
  unsigned short* wxt1 = (unsigned short*)(ob + 33554432);  // 12 MiB
  unsigned short* a1bf = (unsigned short*)(ob);             // 32 MiB, phase B
  float* out = (float*)d_out;
  float* finals = out + 16777216;

  k_convert_x<<<8192, 256, 0, stream>>>(x, xbf, 2097152);
  k_pack_wxT<<<dim3(96, 32, 4), 256, 0, stream>>>(Wx[0], Wx[1], Wx[2], Wx[3], wxt0, wxt1);
  k_pack_whp<<<dim3(640, 4), 256, 0, stream>>>(Wh[0], Wh[1], Wh[2], Wh[3], whp);
  hipMemsetAsync(hxc, 0xFF, 393216, stream);   // never decodes as a valid seq

  for (int layer = 0; layer < 2; ++layer) {
    int K = layer ? 1024 : 512;
    const unsigned short* Ag = layer ? a1bf : xbf;
    const unsigned short* wxt = layer ? wxt1 : wxt0;
    k_gemm<<<dim3(128, 24, 2), 256, 0, stream>>>(Ag, wxt, px, K);
    k_persist<<<128, 512, 0, stream>>>(
        px, whp + (size_t)layer * 2621440, bs[layer * 2], bs[layer * 2 + 1],
        hxc, layer ? nullptr : a1bf, layer ? out : nullptr, finals, layer);
  }
}